// Round 1
// baseline (1908.475 us; speedup 1.0000x reference)
//
#include <hip/hip_runtime.h>
#include <math.h>

#define BB 4
#define TT 4096
#define CE 1024
#define CH 64
#define SCALEF 0.125f  // 64^-0.5

// ---------------- projection: q,k,v = x @ W{q,k,v} ----------------
// grid: (B*T/32) blocks, 192 threads (3 waves: one per matrix).
// thread: m = wave (0=K,1=Q,2=V), c = lane (output dim). 32 rows per block.
__global__ __launch_bounds__(192, 4)
void proj_kernel(const float* __restrict__ x, const float* __restrict__ Wk,
                 const float* __restrict__ Wq, const float* __restrict__ Wv,
                 float* __restrict__ qp, float* __restrict__ kp, float* __restrict__ vp)
{
    const int t = threadIdx.x;
    const int m = t >> 6;
    const int c = t & 63;
    const long row0 = (long)blockIdx.x * 32;
    const float* __restrict__ W = (m == 0) ? Wk : (m == 1 ? Wq : Wv);
    float* __restrict__ outp = (m == 0) ? kp : (m == 1 ? qp : vp);

    float acc[32];
#pragma unroll
    for (int r = 0; r < 32; ++r) acc[r] = 0.f;

    for (int k0 = 0; k0 < CE; k0 += 8) {
        float w8[8];
#pragma unroll
        for (int j = 0; j < 8; ++j) w8[j] = W[(k0 + j) * CH + c];
#pragma unroll
        for (int r = 0; r < 32; ++r) {
            const float* __restrict__ xr = x + (row0 + r) * CE + k0;  // wave-uniform -> s_load
#pragma unroll
            for (int j = 0; j < 8; ++j) acc[r] = fmaf(xr[j], w8[j], acc[r]);
        }
    }
#pragma unroll
    for (int r = 0; r < 32; ++r) outp[(row0 + r) * CH + c] = acc[r];
}

// ---------------- pass 1: per-column max & expsum ----------------
// grid: (B, T/64, 2). 256 threads: lane = column, wave = q-slice (stride 4).
__global__ __launch_bounds__(256, 2)
void colstats_kernel(const float* __restrict__ qp, const float* __restrict__ kp,
                     float* __restrict__ pm, float* __restrict__ pl)
{
    const int b = blockIdx.x;
    const int cb = blockIdx.y;
    const int qs = blockIdx.z;
    const int lane = threadIdx.x & 63;
    const int slice = threadIdx.x >> 6;
    const int k0 = cb * 64;
    const int k = k0 + lane;

    const long qlo = (long)qs * (TT / 2);
    const long qhi = qlo + (TT / 2);
    const long qstart = (qlo > (long)k0) ? qlo : (long)k0;

    float m = -INFINITY;
    float l = 0.f;

    if (qstart < qhi) {
        float kreg[64];
        const float* __restrict__ kptr = kp + ((long)b * TT + k) * CH;
#pragma unroll
        for (int d = 0; d < 64; ++d) kreg[d] = kptr[d];

#pragma unroll 2
        for (long q = qstart + slice; q < qhi; q += 4) {
            const float* __restrict__ qv = qp + ((long)b * TT + q) * CH;  // wave-uniform
            float s = 0.f;
#pragma unroll
            for (int d = 0; d < 64; ++d) s = fmaf(qv[d], kreg[d], s);
            s *= SCALEF;
            if (q >= k) {   // causal: column k gets q >= k
                float mn = fmaxf(m, s);
                l = l * __expf(m - mn) + __expf(s - mn);
                m = mn;
            }
        }
    }

    __shared__ float ms[4][64], ls[4][64];
    ms[slice][lane] = m;
    ls[slice][lane] = l;
    __syncthreads();
    if (threadIdx.x < 64) {
        float mm = ms[0][lane];
#pragma unroll
        for (int i = 1; i < 4; ++i) mm = fmaxf(mm, ms[i][lane]);
        float ll = 0.f;
        if (mm > -INFINITY) {
#pragma unroll
            for (int i = 0; i < 4; ++i) ll += ls[i][lane] * __expf(ms[i][lane] - mm);
        }
        pm[((long)qs * BB + b) * TT + k] = mm;
        pl[((long)qs * BB + b) * TT + k] = ll;
    }
}

// ---------------- combine the 2 q-slice partials ----------------
__global__ __launch_bounds__(256)
void finalize_stats(const float* __restrict__ pm, const float* __restrict__ pl,
                    float* __restrict__ mf, float* __restrict__ linv)
{
    const long i = (long)blockIdx.x * 256 + threadIdx.x;
    const long n = (long)BB * TT;
    float m0 = pm[i], m1 = pm[n + i];
    float l0 = pl[i], l1 = pl[n + i];
    float mm = fmaxf(m0, m1);
    float ll = 0.f;
    if (m0 > -INFINITY) ll += l0 * __expf(m0 - mm);
    if (m1 > -INFINITY) ll += l1 * __expf(m1 - mm);
    mf[i] = mm;
    linv[i] = 1.f / ll;   // every column has at least q=k -> ll > 0
}

// ---------------- pass 2: out[q,:] = sum_k exp(s-m[k])*linv[k] * v[k,:] ----------------
// grid: (B, T/64, 2). lane = query, wave = k-slice (stride 4), grid.z = k-half.
__global__ __launch_bounds__(256, 2)
void pv_kernel(const float* __restrict__ qp, const float* __restrict__ kp,
               const float* __restrict__ vp, const float* __restrict__ mf,
               const float* __restrict__ linv, float* __restrict__ pout)
{
    const int b = blockIdx.x;
    const int qb = blockIdx.y;
    const int ks = blockIdx.z;
    const int lane = threadIdx.x & 63;
    const int slice = threadIdx.x >> 6;
    const long q = (long)qb * 64 + lane;

    const long klo = (long)ks * (TT / 2);
    const long khi = klo + (TT / 2);
    long kend = (long)qb * 64 + 64;      // wave-uniform upper bound (max q + 1)
    if (khi < kend) kend = khi;

    float acc[64];
#pragma unroll
    for (int c = 0; c < 64; ++c) acc[c] = 0.f;

    if (klo < kend) {
        float qreg[64];
        const float* __restrict__ qptr = qp + ((long)b * TT + q) * CH;
#pragma unroll
        for (int d = 0; d < 64; ++d) qreg[d] = qptr[d];

        const long base = (long)b * TT;
        for (long kk = klo + slice; kk < kend; kk += 4) {
            if (kk <= q) {
                const float* __restrict__ kv = kp + (base + kk) * CH;   // wave-uniform
                float s = 0.f;
#pragma unroll
                for (int d = 0; d < 64; ++d) s = fmaf(kv[d], qreg[d], s);
                s *= SCALEF;
                float p = __expf(s - mf[base + kk]) * linv[base + kk];
                const float* __restrict__ vv = vp + (base + kk) * CH;   // wave-uniform
#pragma unroll
                for (int c = 0; c < 64; ++c) acc[c] = fmaf(p, vv[c], acc[c]);
            }
        }
    }

    // reduce the 4 k-slices within the block (two 32-dim rounds, 33 KB LDS)
    __shared__ float red[4][64][33];
#pragma unroll
    for (int half = 0; half < 2; ++half) {
#pragma unroll
        for (int i = 0; i < 32; ++i) red[slice][lane][i] = acc[half * 32 + i];
        __syncthreads();
#pragma unroll
        for (int i = 0; i < 8; ++i) {
            int c = slice * 8 + i;
            float v = red[0][lane][c] + red[1][lane][c] + red[2][lane][c] + red[3][lane][c];
            pout[(((long)ks * BB + b) * TT + q) * CH + half * 32 + c] = v;
        }
        __syncthreads();
    }
}

// ---------------- sum the 2 k-half partial outputs ----------------
__global__ __launch_bounds__(256)
void finalize_out(const float* __restrict__ pout, float* __restrict__ out)
{
    const long i = (long)blockIdx.x * 256 + threadIdx.x;
    const long n4 = (long)BB * TT * CH / 4;
    float4 a = reinterpret_cast<const float4*>(pout)[i];
    float4 c = reinterpret_cast<const float4*>(pout)[n4 + i];
    float4 r;
    r.x = a.x + c.x; r.y = a.y + c.y; r.z = a.z + c.z; r.w = a.w + c.w;
    reinterpret_cast<float4*>(out)[i] = r;
}

extern "C" void kernel_launch(void* const* d_in, const int* in_sizes, int n_in,
                              void* d_out, int out_size, void* d_ws, size_t ws_size,
                              hipStream_t stream)
{
    const float* x  = (const float*)d_in[0];
    const float* Wk = (const float*)d_in[1];
    const float* Wq = (const float*)d_in[2];
    const float* Wv = (const float*)d_in[3];
    float* out = (float*)d_out;

    // workspace layout (floats), total ~20.4 MB
    float* ws = (float*)d_ws;
    const size_t NT = (size_t)BB * TT;            // 16384
    float* qp   = ws;                             // NT*CH
    float* kp   = qp + NT * CH;                   // NT*CH
    float* vp   = kp + NT * CH;                   // NT*CH
    float* pm   = vp + NT * CH;                   // 2*NT
    float* pl   = pm + 2 * NT;                    // 2*NT
    float* mf   = pl + 2 * NT;                    // NT
    float* linv = mf + NT;                        // NT
    float* pout = linv + NT;                      // 2*NT*CH

    hipLaunchKernelGGL(proj_kernel, dim3(NT / 32), dim3(192), 0, stream,
                       x, Wk, Wq, Wv, qp, kp, vp);
    hipLaunchKernelGGL(colstats_kernel, dim3(BB, TT / 64, 2), dim3(256), 0, stream,
                       qp, kp, pm, pl);
    hipLaunchKernelGGL(finalize_stats, dim3(NT / 256), dim3(256), 0, stream,
                       pm, pl, mf, linv);
    hipLaunchKernelGGL(pv_kernel, dim3(BB, TT / 64, 2), dim3(256), 0, stream,
                       qp, kp, vp, mf, linv, pout);
    hipLaunchKernelGGL(finalize_out, dim3(NT * CH / 4 / 256), dim3(256), 0, stream,
                       pout, out);
}

// Round 2
// 518.333 us; speedup vs baseline: 3.6819x; 3.6819x over previous
//
#include <hip/hip_runtime.h>
#include <math.h>

#define BB 4
#define TT 4096
#define CE 1024
#define CH 64
#define SCALEF 0.125f   // 64^-0.5
#define NQT 64          // TT/64 tiles

typedef unsigned short ushort_t;
typedef __attribute__((ext_vector_type(8))) short bf16x8;   // 8 bf16 = 4 VGPR
typedef __attribute__((ext_vector_type(8))) unsigned short u16x8;
typedef __attribute__((ext_vector_type(4))) float f32x4;

__device__ __forceinline__ unsigned short f2bf(float f) {
    unsigned int x = __builtin_bit_cast(unsigned int, f);
    unsigned int r = x + 0x7fffu + ((x >> 16) & 1u);   // RNE
    return (unsigned short)(r >> 16);
}
__device__ __forceinline__ float bf2f(unsigned short u) {
    unsigned int x = ((unsigned int)u) << 16;
    return __builtin_bit_cast(float, x);
}

// ---------------- projection: q,k,v = x @ W{q,k,v}, output bf16 ----------------
__global__ __launch_bounds__(192, 4)
void proj_kernel(const float* __restrict__ x, const float* __restrict__ Wk,
                 const float* __restrict__ Wq, const float* __restrict__ Wv,
                 ushort_t* __restrict__ qb, ushort_t* __restrict__ kb, ushort_t* __restrict__ vb)
{
    const int t = threadIdx.x;
    const int m = t >> 6;
    const int c = t & 63;
    const long row0 = (long)blockIdx.x * 32;
    const float* __restrict__ W = (m == 0) ? Wk : (m == 1 ? Wq : Wv);
    ushort_t* __restrict__ outp = (m == 0) ? kb : (m == 1 ? qb : vb);

    float acc[32];
#pragma unroll
    for (int r = 0; r < 32; ++r) acc[r] = 0.f;

    for (int k0 = 0; k0 < CE; k0 += 8) {
        float w8[8];
#pragma unroll
        for (int j = 0; j < 8; ++j) w8[j] = W[(k0 + j) * CH + c];
#pragma unroll
        for (int r = 0; r < 32; ++r) {
            const float* __restrict__ xr = x + (row0 + r) * CE + k0;  // wave-uniform
#pragma unroll
            for (int j = 0; j < 8; ++j) acc[r] = fmaf(xr[j], w8[j], acc[r]);
        }
    }
#pragma unroll
    for (int r = 0; r < 32; ++r) outp[(row0 + r) * CH + c] = f2bf(acc[r]);
}

// ---------------- pass 1: per-column (k) max & expsum via MFMA ----------------
// grid (BB, 32, 2): pair (kt=p, kt=63-p), z = q-tile parity. 4 waves.
// Wave w owns k-rows [kt*64+w*16, +16). S^T tile: D row = k (lg*4+r), D col = q (qf*16+lr).
__global__ __launch_bounds__(256)
void colstats_mfma(const ushort_t* __restrict__ qb, const ushort_t* __restrict__ kb,
                   float* __restrict__ pm, float* __restrict__ pl)
{
    const int b = blockIdx.x, p = blockIdx.y, z = blockIdx.z;
    const int w = threadIdx.x >> 6, l = threadIdx.x & 63, lg = l >> 4, lr = l & 15;
    const long baseT = (long)b * TT;
    const long NTT = (long)BB * TT;

    for (int pass = 0; pass < 2; ++pass) {
        const int kt = pass ? (63 - p) : p;
        const ushort_t* kptr = kb + (baseT + (long)kt * 64 + w * 16 + lr) * CH + lg * 8;
        bf16x8 ka0 = *(const bf16x8*)kptr;
        bf16x8 ka1 = *(const bf16x8*)(kptr + 32);

        float m_r[4] = {-INFINITY, -INFINITY, -INFINITY, -INFINITY};
        float l_r[4] = {0.f, 0.f, 0.f, 0.f};

        const int j0 = kt + (((kt & 1) == z) ? 0 : 1);
        for (int j = j0; j < NQT; j += 2) {
            const bool diag = (j == kt);
            float sv[4][4];
#pragma unroll
            for (int qf = 0; qf < 4; ++qf) {
                const ushort_t* qptr = qb + (baseT + (long)j * 64 + qf * 16 + lr) * CH + lg * 8;
                bf16x8 b0 = *(const bf16x8*)qptr;
                bf16x8 b1 = *(const bf16x8*)(qptr + 32);
                f32x4 s = {0.f, 0.f, 0.f, 0.f};
                s = __builtin_amdgcn_mfma_f32_16x16x32_bf16(ka0, b0, s, 0, 0, 0);
                s = __builtin_amdgcn_mfma_f32_16x16x32_bf16(ka1, b1, s, 0, 0, 0);
#pragma unroll
                for (int r = 0; r < 4; ++r) {
                    float v = s[r] * SCALEF;
                    if (diag && (qf * 16 + lr) < (w * 16 + lg * 4 + r)) v = -INFINITY;
                    sv[qf][r] = v;
                }
            }
#pragma unroll
            for (int r = 0; r < 4; ++r) {
                float tm = fmaxf(fmaxf(sv[0][r], sv[1][r]), fmaxf(sv[2][r], sv[3][r]));
                float mn = fmaxf(m_r[r], tm);
                if (mn > -INFINITY) {
                    float e = __expf(sv[0][r] - mn) + __expf(sv[1][r] - mn)
                            + __expf(sv[2][r] - mn) + __expf(sv[3][r] - mn);
                    l_r[r] = l_r[r] * __expf(m_r[r] - mn) + e;
                    m_r[r] = mn;
                }
            }
        }
        // reduce over the 16-lane q dimension (xor masks stay within 16-groups)
#pragma unroll
        for (int r = 0; r < 4; ++r) {
            float m = m_r[r], lv = l_r[r];
            for (int d = 1; d < 16; d <<= 1) {
                float om = __shfl_xor(m, d);
                float ol = __shfl_xor(lv, d);
                float mn = fmaxf(m, om);
                if (mn > -INFINITY)
                    lv = lv * __expf(m - mn) + ol * __expf(om - mn);
                m = mn;
            }
            if (lr == 0) {
                const long k = (long)kt * 64 + w * 16 + lg * 4 + r;
                pm[(long)z * NTT + baseT + k] = m;
                pl[(long)z * NTT + baseT + k] = lv;
            }
        }
    }
}

// ---------------- combine the 2 parity partials ----------------
__global__ __launch_bounds__(256)
void finalize_stats(const float* __restrict__ pm, const float* __restrict__ pl,
                    float* __restrict__ mf, float* __restrict__ linv)
{
    const long i = (long)blockIdx.x * 256 + threadIdx.x;
    const long NTT = (long)BB * TT;
    float m0 = pm[i], m1 = pm[NTT + i];
    float l0 = pl[i], l1 = pl[NTT + i];
    float mm = fmaxf(m0, m1);
    float ll = 0.f;
    if (m0 > -INFINITY) ll += l0 * __expf(m0 - mm);
    if (m1 > -INFINITY) ll += l1 * __expf(m1 - mm);
    mf[i] = mm;
    linv[i] = 1.f / ll;
}

// ---------------- VT[c][t] = v[t][c] * linv[t]  (bf16, transposed) ----------------
__global__ __launch_bounds__(256)
void vt_scale(const ushort_t* __restrict__ vb, const float* __restrict__ linv,
              ushort_t* __restrict__ vtb)
{
    const int b = blockIdx.x;
    const long t0 = (long)blockIdx.y * 64;
    const int tid = threadIdx.x;
    __shared__ ushort_t lds[64][72];
    const long baseT = (long)b * TT;
#pragma unroll
    for (int i = 0; i < 2; ++i) {
        const int t = i * 32 + (tid >> 3);
        const int c0 = (tid & 7) * 8;
        u16x8 v = *(const u16x8*)(vb + (baseT + t0 + t) * CH + c0);
        const float sc = linv[baseT + t0 + t];
#pragma unroll
        for (int j = 0; j < 8; ++j) lds[c0 + j][t] = f2bf(bf2f(v[j]) * sc);
    }
    __syncthreads();
#pragma unroll
    for (int i = 0; i < 2; ++i) {
        const int c = i * 32 + (tid >> 3);
        const int tt0 = (tid & 7) * 8;
        u16x8 ov = *(const u16x8*)&lds[c][tt0];
        *(u16x8*)(vtb + ((long)b * 64 + c) * TT + t0 + tt0) = ov;
    }
}

// ---------------- pass 2: O^T = (linv*V)^T @ P^T, P = exp(s - m[k]) masked ----------------
// grid (BB, 32, 2): pair (qt=p, qt=63-p), z = k-tile parity. 4 waves.
__global__ __launch_bounds__(256)
void pv_mfma(const ushort_t* __restrict__ qb, const ushort_t* __restrict__ kb,
             const ushort_t* __restrict__ vtb, const float* __restrict__ mf,
             float* __restrict__ pout)
{
    const int b = blockIdx.x, p = blockIdx.y, z = blockIdx.z;
    const int w = threadIdx.x >> 6, l = threadIdx.x & 63, lg = l >> 4, lr = l & 15;
    const long baseT = (long)b * TT;
    const long NTT = (long)BB * TT;
    __shared__ ushort_t plds[64][72];   // [q][k], padded: 2-way banks only

    for (int pass = 0; pass < 2; ++pass) {
        const int qt = pass ? (63 - p) : p;
        // hoist Q fragments (B-operand of S^T) for this q-tile
        bf16x8 qf_[4][2];
#pragma unroll
        for (int qf = 0; qf < 4; ++qf) {
            const ushort_t* qptr = qb + (baseT + (long)qt * 64 + qf * 16 + lr) * CH + lg * 8;
            qf_[qf][0] = *(const bf16x8*)qptr;
            qf_[qf][1] = *(const bf16x8*)(qptr + 32);
        }
        f32x4 o[4];
#pragma unroll
        for (int qf = 0; qf < 4; ++qf) o[qf] = (f32x4){0.f, 0.f, 0.f, 0.f};

        for (int j = z; j <= qt; j += 2) {
            // S^T: A = K rows (this wave's 16 k-tokens)
            const ushort_t* kptr = kb + (baseT + (long)j * 64 + w * 16 + lr) * CH + lg * 8;
            bf16x8 ka0 = *(const bf16x8*)kptr;
            bf16x8 ka1 = *(const bf16x8*)(kptr + 32);
            float mrow[4];
#pragma unroll
            for (int r = 0; r < 4; ++r)
                mrow[r] = mf[baseT + (long)j * 64 + w * 16 + lg * 4 + r];
            const bool diag = (j == qt);
#pragma unroll
            for (int qf = 0; qf < 4; ++qf) {
                f32x4 s = {0.f, 0.f, 0.f, 0.f};
                s = __builtin_amdgcn_mfma_f32_16x16x32_bf16(ka0, qf_[qf][0], s, 0, 0, 0);
                s = __builtin_amdgcn_mfma_f32_16x16x32_bf16(ka1, qf_[qf][1], s, 0, 0, 0);
                unsigned short e[4];
#pragma unroll
                for (int r = 0; r < 4; ++r) {
                    float ev = __expf(s[r] * SCALEF - mrow[r]);
                    if (diag && (qf * 16 + lr) < (w * 16 + lg * 4 + r)) ev = 0.f;
                    e[r] = f2bf(ev);
                }
                uint2 pk;
                pk.x = (unsigned)e[0] | ((unsigned)e[1] << 16);
                pk.y = (unsigned)e[2] | ((unsigned)e[3] << 16);
                *(uint2*)&plds[qf * 16 + lr][w * 16 + lg * 4] = pk;  // [q][k], k packed x4
            }
            __syncthreads();
            // O^T += VT @ P^T : A = VT rows (this wave's 16 channels), B = P from LDS
            const ushort_t* vptr = vtb + ((long)b * 64 + w * 16 + lr) * TT + (long)j * 64 + lg * 8;
            bf16x8 va0 = *(const bf16x8*)vptr;
            bf16x8 va1 = *(const bf16x8*)(vptr + 32);
#pragma unroll
            for (int qf = 0; qf < 4; ++qf) {
                bf16x8 p0 = *(const bf16x8*)&plds[qf * 16 + lr][lg * 8];
                bf16x8 p1 = *(const bf16x8*)&plds[qf * 16 + lr][32 + lg * 8];
                o[qf] = __builtin_amdgcn_mfma_f32_16x16x32_bf16(va0, p0, o[qf], 0, 0, 0);
                o[qf] = __builtin_amdgcn_mfma_f32_16x16x32_bf16(va1, p1, o[qf], 0, 0, 0);
            }
            __syncthreads();
        }
        // store O^T frag: c = w*16 + lg*4 + r (consecutive in r -> float4), q = qf*16+lr
        float* pz = pout + ((long)z * NTT + baseT + (long)qt * 64) * CH;
#pragma unroll
        for (int qf = 0; qf < 4; ++qf)
            *(f32x4*)(pz + (long)(qf * 16 + lr) * CH + w * 16 + lg * 4) = o[qf];
    }
}

// ---------------- sum the 2 parity partial outputs ----------------
__global__ __launch_bounds__(256)
void finalize_out(const float* __restrict__ pout, float* __restrict__ out)
{
    const long i = (long)blockIdx.x * 256 + threadIdx.x;
    const long n4 = (long)BB * TT * CH / 4;
    float4 a = reinterpret_cast<const float4*>(pout)[i];
    float4 c = reinterpret_cast<const float4*>(pout)[n4 + i];
    float4 r;
    r.x = a.x + c.x; r.y = a.y + c.y; r.z = a.z + c.z; r.w = a.w + c.w;
    reinterpret_cast<float4*>(out)[i] = r;
}

extern "C" void kernel_launch(void* const* d_in, const int* in_sizes, int n_in,
                              void* d_out, int out_size, void* d_ws, size_t ws_size,
                              hipStream_t stream)
{
    const float* x  = (const float*)d_in[0];
    const float* Wk = (const float*)d_in[1];
    const float* Wq = (const float*)d_in[2];
    const float* Wv = (const float*)d_in[3];
    float* out = (float*)d_out;

    const size_t NT = (size_t)BB * TT;   // 16384
    ushort_t* qb  = (ushort_t*)d_ws;     // NT*CH bf16
    ushort_t* kb  = qb + NT * CH;
    ushort_t* vb  = kb + NT * CH;
    ushort_t* vtb = vb + NT * CH;
    float* pm   = (float*)(vtb + NT * CH);  // 2*NT
    float* pl   = pm + 2 * NT;              // 2*NT
    float* mf   = pl + 2 * NT;              // NT
    float* linv = mf + NT;                  // NT
    float* pout = linv + NT;                // 2*NT*CH

    hipLaunchKernelGGL(proj_kernel, dim3(NT / 32), dim3(192), 0, stream,
                       x, Wk, Wq, Wv, qb, kb, vb);
    hipLaunchKernelGGL(colstats_mfma, dim3(BB, NQT / 2, 2), dim3(256), 0, stream,
                       qb, kb, pm, pl);
    hipLaunchKernelGGL(finalize_stats, dim3(NT / 256), dim3(256), 0, stream,
                       pm, pl, mf, linv);
    hipLaunchKernelGGL(vt_scale, dim3(BB, TT / 64), dim3(256), 0, stream,
                       vb, linv, vtb);
    hipLaunchKernelGGL(pv_mfma, dim3(BB, NQT / 2, 2), dim3(256), 0, stream,
                       qb, kb, vtb, mf, pout);
    hipLaunchKernelGGL(finalize_out, dim3(NT * CH / 4 / 256), dim3(256), 0, stream,
                       pout, out);
}

// Round 3
// 168.762 us; speedup vs baseline: 11.3087x; 3.0714x over previous
//
#include <hip/hip_runtime.h>
#include <math.h>

#define BB 4
#define TT 4096
#define CE 1024
#define CH 64
#define SCALEF 0.125f   // 64^-0.5
#define NQT 64          // TT/64 tiles

typedef unsigned short ushort_t;
typedef __attribute__((ext_vector_type(8))) short bf16x8;   // 8 bf16 = 4 VGPR
typedef __attribute__((ext_vector_type(8))) unsigned short u16x8;
typedef __attribute__((ext_vector_type(4))) float f32x4;

__device__ __forceinline__ unsigned short f2bf(float f) {
    unsigned int x = __builtin_bit_cast(unsigned int, f);
    unsigned int r = x + 0x7fffu + ((x >> 16) & 1u);   // RNE
    return (unsigned short)(r >> 16);
}
__device__ __forceinline__ float bf2f(unsigned short u) {
    unsigned int x = ((unsigned int)u) << 16;
    return __builtin_bit_cast(float, x);
}

// ---------------- build WT[m*64 + c][k] = bf16(W_m[k][c]) ----------------
// grid (3, 16), 256 threads. LDS transpose, coalesced both sides.
__global__ __launch_bounds__(256)
void wt_build(const float* __restrict__ Wk, const float* __restrict__ Wq,
              const float* __restrict__ Wv, ushort_t* __restrict__ wt)
{
    const int m = blockIdx.x, kt = blockIdx.y;
    const float* __restrict__ W = (m == 0) ? Wk : (m == 1 ? Wq : Wv);
    const int k0 = kt * 64;
    __shared__ float lds[64][65];
    const int cc = threadIdx.x & 63, g = threadIdx.x >> 6;
#pragma unroll
    for (int i = 0; i < 16; ++i) {
        const int r = g * 16 + i;
        lds[r][cc] = W[(k0 + r) * CH + cc];
    }
    __syncthreads();
#pragma unroll
    for (int i = 0; i < 16; ++i) {
        const int c = g * 16 + i;
        wt[((long)(m * 64 + c)) * CE + k0 + cc] = f2bf(lds[cc][c]);
    }
}

// ---------------- projection via MFMA: out[t][c] = sum_k x[t][k] * W[k][c] ----------------
// grid 1024 (16 tokens each), 192 threads = 3 waves (wave = matrix).
// A-frag: x rows (lr = token, lg*8 = k-dim), converted f32->bf16 in-register.
// B-frag: WT rows (lr = out-col, lg*8 = k-dim), contiguous bf16x8, L2-resident.
__global__ __launch_bounds__(192)
void proj_mfma(const float* __restrict__ x, const ushort_t* __restrict__ wt,
               ushort_t* __restrict__ qb, ushort_t* __restrict__ kb, ushort_t* __restrict__ vb)
{
    const int w = threadIdx.x >> 6, l = threadIdx.x & 63, lg = l >> 4, lr = l & 15;
    const long t0 = (long)blockIdx.x * 16;
    ushort_t* __restrict__ outp = (w == 0) ? kb : (w == 1 ? qb : vb);
    const float* __restrict__ xr = x + (t0 + lr) * CE;
    const ushort_t* __restrict__ wbase = wt + ((long)(w * 64 + lr)) * CE;

    f32x4 acc[4];
#pragma unroll
    for (int nf = 0; nf < 4; ++nf) acc[nf] = (f32x4){0.f, 0.f, 0.f, 0.f};

#pragma unroll 2
    for (int k0 = 0; k0 < CE; k0 += 32) {
        float4 a0 = *(const float4*)(xr + k0 + lg * 8);
        float4 a1 = *(const float4*)(xr + k0 + lg * 8 + 4);
        bf16x8 af;
        af[0] = (short)f2bf(a0.x); af[1] = (short)f2bf(a0.y);
        af[2] = (short)f2bf(a0.z); af[3] = (short)f2bf(a0.w);
        af[4] = (short)f2bf(a1.x); af[5] = (short)f2bf(a1.y);
        af[6] = (short)f2bf(a1.z); af[7] = (short)f2bf(a1.w);
#pragma unroll
        for (int nf = 0; nf < 4; ++nf) {
            bf16x8 bfrag = *(const bf16x8*)(wbase + (long)nf * 16 * CE + k0 + lg * 8);
            acc[nf] = __builtin_amdgcn_mfma_f32_16x16x32_bf16(af, bfrag, acc[nf], 0, 0, 0);
        }
    }
    // D: row(token) = lg*4 + r, col = nf*16 + lr
#pragma unroll
    for (int nf = 0; nf < 4; ++nf)
#pragma unroll
        for (int r = 0; r < 4; ++r)
            outp[(t0 + lg * 4 + r) * CH + nf * 16 + lr] = f2bf(acc[nf][r]);
}

// ---------------- pass 1: per-column (k) max & expsum via MFMA ----------------
// grid (BB, 32, 2): pair (kt=p, kt=63-p), z = q-tile parity. 4 waves.
__global__ __launch_bounds__(256)
void colstats_mfma(const ushort_t* __restrict__ qb, const ushort_t* __restrict__ kb,
                   float* __restrict__ pm, float* __restrict__ pl)
{
    const int b = blockIdx.x, p = blockIdx.y, z = blockIdx.z;
    const int w = threadIdx.x >> 6, l = threadIdx.x & 63, lg = l >> 4, lr = l & 15;
    const long baseT = (long)b * TT;
    const long NTT = (long)BB * TT;

    for (int pass = 0; pass < 2; ++pass) {
        const int kt = pass ? (63 - p) : p;
        const ushort_t* kptr = kb + (baseT + (long)kt * 64 + w * 16 + lr) * CH + lg * 8;
        bf16x8 ka0 = *(const bf16x8*)kptr;
        bf16x8 ka1 = *(const bf16x8*)(kptr + 32);

        float m_r[4] = {-INFINITY, -INFINITY, -INFINITY, -INFINITY};
        float l_r[4] = {0.f, 0.f, 0.f, 0.f};

        const int j0 = kt + (((kt & 1) == z) ? 0 : 1);
        for (int j = j0; j < NQT; j += 2) {
            const bool diag = (j == kt);
            float sv[4][4];
#pragma unroll
            for (int qf = 0; qf < 4; ++qf) {
                const ushort_t* qptr = qb + (baseT + (long)j * 64 + qf * 16 + lr) * CH + lg * 8;
                bf16x8 b0 = *(const bf16x8*)qptr;
                bf16x8 b1 = *(const bf16x8*)(qptr + 32);
                f32x4 s = {0.f, 0.f, 0.f, 0.f};
                s = __builtin_amdgcn_mfma_f32_16x16x32_bf16(ka0, b0, s, 0, 0, 0);
                s = __builtin_amdgcn_mfma_f32_16x16x32_bf16(ka1, b1, s, 0, 0, 0);
#pragma unroll
                for (int r = 0; r < 4; ++r) {
                    float v = s[r] * SCALEF;
                    if (diag && (qf * 16 + lr) < (w * 16 + lg * 4 + r)) v = -INFINITY;
                    sv[qf][r] = v;
                }
            }
#pragma unroll
            for (int r = 0; r < 4; ++r) {
                float tm = fmaxf(fmaxf(sv[0][r], sv[1][r]), fmaxf(sv[2][r], sv[3][r]));
                float mn = fmaxf(m_r[r], tm);
                if (mn > -INFINITY) {
                    float e = __expf(sv[0][r] - mn) + __expf(sv[1][r] - mn)
                            + __expf(sv[2][r] - mn) + __expf(sv[3][r] - mn);
                    l_r[r] = l_r[r] * __expf(m_r[r] - mn) + e;
                    m_r[r] = mn;
                }
            }
        }
        // reduce over the 16-lane q dimension (xor masks stay within 16-groups)
#pragma unroll
        for (int r = 0; r < 4; ++r) {
            float m = m_r[r], lv = l_r[r];
            for (int d = 1; d < 16; d <<= 1) {
                float om = __shfl_xor(m, d);
                float ol = __shfl_xor(lv, d);
                float mn = fmaxf(m, om);
                if (mn > -INFINITY)
                    lv = lv * __expf(m - mn) + ol * __expf(om - mn);
                m = mn;
            }
            if (lr == 0) {
                const long k = (long)kt * 64 + w * 16 + lg * 4 + r;
                pm[(long)z * NTT + baseT + k] = m;
                pl[(long)z * NTT + baseT + k] = lv;
            }
        }
    }
}

// ---------------- combine the 2 parity partials ----------------
__global__ __launch_bounds__(256)
void finalize_stats(const float* __restrict__ pm, const float* __restrict__ pl,
                    float* __restrict__ mf, float* __restrict__ linv)
{
    const long i = (long)blockIdx.x * 256 + threadIdx.x;
    const long NTT = (long)BB * TT;
    float m0 = pm[i], m1 = pm[NTT + i];
    float l0 = pl[i], l1 = pl[NTT + i];
    float mm = fmaxf(m0, m1);
    float ll = 0.f;
    if (m0 > -INFINITY) ll += l0 * __expf(m0 - mm);
    if (m1 > -INFINITY) ll += l1 * __expf(m1 - mm);
    mf[i] = mm;
    linv[i] = 1.f / ll;
}

// ---------------- VT[c][t] = v[t][c] * linv[t]  (bf16, transposed) ----------------
__global__ __launch_bounds__(256)
void vt_scale(const ushort_t* __restrict__ vb, const float* __restrict__ linv,
              ushort_t* __restrict__ vtb)
{
    const int b = blockIdx.x;
    const long t0 = (long)blockIdx.y * 64;
    const int tid = threadIdx.x;
    __shared__ ushort_t lds[64][72];
    const long baseT = (long)b * TT;
#pragma unroll
    for (int i = 0; i < 2; ++i) {
        const int t = i * 32 + (tid >> 3);
        const int c0 = (tid & 7) * 8;
        u16x8 v = *(const u16x8*)(vb + (baseT + t0 + t) * CH + c0);
        const float sc = linv[baseT + t0 + t];
#pragma unroll
        for (int j = 0; j < 8; ++j) lds[c0 + j][t] = f2bf(bf2f(v[j]) * sc);
    }
    __syncthreads();
#pragma unroll
    for (int i = 0; i < 2; ++i) {
        const int c = i * 32 + (tid >> 3);
        const int tt0 = (tid & 7) * 8;
        u16x8 ov = *(const u16x8*)&lds[c][tt0];
        *(u16x8*)(vtb + ((long)b * 64 + c) * TT + t0 + tt0) = ov;
    }
}

// ---------------- pass 2: O^T = (linv*V)^T @ P^T, P = exp(s - m[k]) masked ----------------
// grid (BB, 32, 2): pair (qt=p, qt=63-p), z = k-tile parity. 4 waves.
__global__ __launch_bounds__(256)
void pv_mfma(const ushort_t* __restrict__ qb, const ushort_t* __restrict__ kb,
             const ushort_t* __restrict__ vtb, const float* __restrict__ mf,
             float* __restrict__ pout)
{
    const int b = blockIdx.x, p = blockIdx.y, z = blockIdx.z;
    const int w = threadIdx.x >> 6, l = threadIdx.x & 63, lg = l >> 4, lr = l & 15;
    const long baseT = (long)b * TT;
    const long NTT = (long)BB * TT;
    __shared__ ushort_t plds[64][72];   // [q][k], padded: 2-way banks only

    for (int pass = 0; pass < 2; ++pass) {
        const int qt = pass ? (63 - p) : p;
        // hoist Q fragments (B-operand of S^T) for this q-tile
        bf16x8 qf_[4][2];
#pragma unroll
        for (int qf = 0; qf < 4; ++qf) {
            const ushort_t* qptr = qb + (baseT + (long)qt * 64 + qf * 16 + lr) * CH + lg * 8;
            qf_[qf][0] = *(const bf16x8*)qptr;
            qf_[qf][1] = *(const bf16x8*)(qptr + 32);
        }
        f32x4 o[4];
#pragma unroll
        for (int qf = 0; qf < 4; ++qf) o[qf] = (f32x4){0.f, 0.f, 0.f, 0.f};

        for (int j = z; j <= qt; j += 2) {
            // S^T: A = K rows (this wave's 16 k-tokens)
            const ushort_t* kptr = kb + (baseT + (long)j * 64 + w * 16 + lr) * CH + lg * 8;
            bf16x8 ka0 = *(const bf16x8*)kptr;
            bf16x8 ka1 = *(const bf16x8*)(kptr + 32);
            float mrow[4];
#pragma unroll
            for (int r = 0; r < 4; ++r)
                mrow[r] = mf[baseT + (long)j * 64 + w * 16 + lg * 4 + r];
            const bool diag = (j == qt);
#pragma unroll
            for (int qf = 0; qf < 4; ++qf) {
                f32x4 s = {0.f, 0.f, 0.f, 0.f};
                s = __builtin_amdgcn_mfma_f32_16x16x32_bf16(ka0, qf_[qf][0], s, 0, 0, 0);
                s = __builtin_amdgcn_mfma_f32_16x16x32_bf16(ka1, qf_[qf][1], s, 0, 0, 0);
                unsigned short e[4];
#pragma unroll
                for (int r = 0; r < 4; ++r) {
                    float ev = __expf(s[r] * SCALEF - mrow[r]);
                    if (diag && (qf * 16 + lr) < (w * 16 + lg * 4 + r)) ev = 0.f;
                    e[r] = f2bf(ev);
                }
                uint2 pk;
                pk.x = (unsigned)e[0] | ((unsigned)e[1] << 16);
                pk.y = (unsigned)e[2] | ((unsigned)e[3] << 16);
                *(uint2*)&plds[qf * 16 + lr][w * 16 + lg * 4] = pk;  // [q][k], k packed x4
            }
            __syncthreads();
            // O^T += VT @ P^T : A = VT rows (this wave's 16 channels), B = P from LDS
            const ushort_t* vptr = vtb + ((long)b * 64 + w * 16 + lr) * TT + (long)j * 64 + lg * 8;
            bf16x8 va0 = *(const bf16x8*)vptr;
            bf16x8 va1 = *(const bf16x8*)(vptr + 32);
#pragma unroll
            for (int qf = 0; qf < 4; ++qf) {
                bf16x8 p0 = *(const bf16x8*)&plds[qf * 16 + lr][lg * 8];
                bf16x8 p1 = *(const bf16x8*)&plds[qf * 16 + lr][32 + lg * 8];
                o[qf] = __builtin_amdgcn_mfma_f32_16x16x32_bf16(va0, p0, o[qf], 0, 0, 0);
                o[qf] = __builtin_amdgcn_mfma_f32_16x16x32_bf16(va1, p1, o[qf], 0, 0, 0);
            }
            __syncthreads();
        }
        // store O^T frag: c = w*16 + lg*4 + r (consecutive in r -> float4), q = qf*16+lr
        float* pz = pout + ((long)z * NTT + baseT + (long)qt * 64) * CH;
#pragma unroll
        for (int qf = 0; qf < 4; ++qf)
            *(f32x4*)(pz + (long)(qf * 16 + lr) * CH + w * 16 + lg * 4) = o[qf];
    }
}

// ---------------- sum the 2 parity partial outputs ----------------
__global__ __launch_bounds__(256)
void finalize_out(const float* __restrict__ pout, float* __restrict__ out)
{
    const long i = (long)blockIdx.x * 256 + threadIdx.x;
    const long n4 = (long)BB * TT * CH / 4;
    float4 a = reinterpret_cast<const float4*>(pout)[i];
    float4 c = reinterpret_cast<const float4*>(pout)[n4 + i];
    float4 r;
    r.x = a.x + c.x; r.y = a.y + c.y; r.z = a.z + c.z; r.w = a.w + c.w;
    reinterpret_cast<float4*>(out)[i] = r;
}

extern "C" void kernel_launch(void* const* d_in, const int* in_sizes, int n_in,
                              void* d_out, int out_size, void* d_ws, size_t ws_size,
                              hipStream_t stream)
{
    const float* x  = (const float*)d_in[0];
    const float* Wk = (const float*)d_in[1];
    const float* Wq = (const float*)d_in[2];
    const float* Wv = (const float*)d_in[3];
    float* out = (float*)d_out;

    const size_t NT = (size_t)BB * TT;   // 16384
    ushort_t* qb  = (ushort_t*)d_ws;     // NT*CH bf16
    ushort_t* kb  = qb + NT * CH;
    ushort_t* vb  = kb + NT * CH;
    ushort_t* vtb = vb + NT * CH;
    ushort_t* wt  = vtb + NT * CH;          // 3*64*1024 bf16
    float* pm   = (float*)(wt + 3 * 64 * CE);  // 2*NT
    float* pl   = pm + 2 * NT;              // 2*NT
    float* mf   = pl + 2 * NT;              // NT
    float* linv = mf + NT;                  // NT
    float* pout = linv + NT;                // 2*NT*CH

    hipLaunchKernelGGL(wt_build, dim3(3, 16), dim3(256), 0, stream,
                       Wk, Wq, Wv, wt);
    hipLaunchKernelGGL(proj_mfma, dim3(NT / 16), dim3(192), 0, stream,
                       x, wt, qb, kb, vb);
    hipLaunchKernelGGL(colstats_mfma, dim3(BB, NQT / 2, 2), dim3(256), 0, stream,
                       qb, kb, pm, pl);
    hipLaunchKernelGGL(finalize_stats, dim3(NT / 256), dim3(256), 0, stream,
                       pm, pl, mf, linv);
    hipLaunchKernelGGL(vt_scale, dim3(BB, TT / 64), dim3(256), 0, stream,
                       vb, linv, vtb);
    hipLaunchKernelGGL(pv_mfma, dim3(BB, NQT / 2, 2), dim3(256), 0, stream,
                       qb, kb, vtb, mf, pout);
    hipLaunchKernelGGL(finalize_out, dim3(NT * CH / 4 / 256), dim3(256), 0, stream,
                       pout, out);
}